// Round 7
// baseline (489.397 us; speedup 1.0000x reference)
//
#include <hip/hip_runtime.h>
#include <math.h>

typedef short bf16x8 __attribute__((ext_vector_type(8)));
typedef float f32x4  __attribute__((ext_vector_type(4)));
typedef unsigned short u16;
typedef unsigned int   u32;

#define MFMA16 __builtin_amdgcn_mfma_f32_16x16x32_bf16

__device__ __forceinline__ u16 f2b(float x) {   // fp32 -> bf16 RNE
    union { float f; unsigned u; } v; v.f = x;
    unsigned r = v.u + 0x7fffu + ((v.u >> 16) & 1u);
    return (u16)(r >> 16);
}
__device__ __forceinline__ float b2f(u16 h) {
    union { unsigned u; float f; } v; v.u = ((unsigned)h) << 16;
    return v.f;
}
__device__ __forceinline__ float blo(u32 w) {
    union { u32 u; float f; } v; v.u = w << 16; return v.f;
}
__device__ __forceinline__ float bhi(u32 w) {
    union { u32 u; float f; } v; v.u = w & 0xffff0000u; return v.f;
}
// sum 3 packed bf16 pairs in fp32 (order: i0+i1+i2, matches K3), repack bf16
__device__ __forceinline__ u32 add3pack(u32 x, u32 y, u32 z) {
    float lo = blo(x) + blo(y) + blo(z);
    float hi = bhi(x) + bhi(y) + bhi(z);
    return (u32)f2b(lo) | ((u32)f2b(hi) << 16);
}

// ---------------------------------------------------------------------------
// K0: pre-swizzle weights (bf16, B-fragment panel layout) into global ws.
// Panel(kt,nt): 16 n-rows x 40 u16 (pad 32->40). SWZ layout:
//   WB [0,5120) | V1B [5120,15360) | V2B [15360,20480)
// ---------------------------------------------------------------------------
__global__ __launch_bounds__(256) void swizzle_weights(
    const float* __restrict__ Wg, const float* __restrict__ V1g,
    const float* __restrict__ V2g, u16* __restrict__ SWZ)
{
    int idx = blockIdx.x * 256 + threadIdx.x;       // 0..8191
    int k = idx >> 6, n = idx & 63;
    int off = ((k >> 5) * 4 + (n >> 4)) * 640 + (n & 15) * 40 + ((k >> 3) & 3) * 8 + (k & 7);
    SWZ[5120 + off] = f2b(V1g[idx]);
    if (idx < 4096) {
        SWZ[off]         = f2b(Wg[idx]);
        SWZ[15360 + off] = f2b(V2g[idx]);
    }
}

// ---------------------------------------------------------------------------
// K1: node MLP -> hb (bf16) [N,64]
// ---------------------------------------------------------------------------
__global__ __launch_bounds__(256) void node_mlp_kernel(
    const float* __restrict__ x, const float* __restrict__ u,
    const int* __restrict__ batch,
    const float* __restrict__ W1, const float* __restrict__ b1,
    const float* __restrict__ W2, const float* __restrict__ b2,
    const float* __restrict__ W3, const float* __restrict__ b3,
    u16* __restrict__ hb, int N)
{
    __shared__ float inbuf[4][10];
    __shared__ float h1[4][64];
    __shared__ float h2[4][64];
    const int tid = threadIdx.x;
    const int ni = tid >> 6, f = tid & 63;
    int node = blockIdx.x * 4 + ni;
    if (node >= N) node = N - 1;
    if (f < 6)       inbuf[ni][f] = x[node * 6 + f];
    else if (f < 10) inbuf[ni][f] = u[batch[node] * 4 + (f - 6)];
    __syncthreads();
    float acc = b1[f];
    #pragma unroll
    for (int k = 0; k < 10; ++k) acc = fmaf(inbuf[ni][k], W1[k * 64 + f], acc);
    h1[ni][f] = fmaxf(acc, 0.f);
    __syncthreads();
    acc = b2[f];
    #pragma unroll 16
    for (int k = 0; k < 64; ++k) acc = fmaf(h1[ni][k], W2[k * 64 + f], acc);
    h2[ni][f] = fmaxf(acc, 0.f);
    __syncthreads();
    acc = b3[f];
    #pragma unroll 16
    for (int k = 0; k < 64; ++k) acc = fmaf(h2[ni][k], W3[k * 64 + f], acc);
    hb[node * 64 + f] = f2b(acc);
}

// ---------------------------------------------------------------------------
// K2: segment boundaries (batch_hyper sorted)
// ---------------------------------------------------------------------------
__global__ __launch_bounds__(256) void seg_bounds_kernel(
    const int* __restrict__ bh, int E, int G, int* __restrict__ seg_start)
{
    int g = blockIdx.x * blockDim.x + threadIdx.x;
    if (g > G) return;
    int lo = 0, hi = E;
    while (lo < hi) {
        int mid = (lo + hi) >> 1;
        if (bh[mid] < g) lo = mid + 1; else hi = mid;
    }
    seg_start[g] = lo;
}

// ---------------------------------------------------------------------------
// K3: softmax denominators only (Xh materialization removed; K4 re-gathers
// from L2-resident hb). 4 chunks x 4 sub-edges per wave-iter via clamped
// unconditional loads -> 12 gathers in flight; accumulate predicated.
// exp of the bf16-ROUNDED sum (must match K4's add3pack exactly).
// Also writes out[E..2E) = (float)g coalesced.
// ---------------------------------------------------------------------------
__global__ __launch_bounds__(256) void gather_stats_kernel(
    const u16* __restrict__ hb, const int* __restrict__ hidx,
    const int* __restrict__ seg_start,
    float* __restrict__ Sinv, float* __restrict__ out, int E)
{
    __shared__ float ps[4][16][4];
    const int tid = threadIdx.x, lane = tid & 63, wid = tid >> 6;
    const int sub = lane >> 4, cl = lane & 15;
    const int g = blockIdx.x;
    const int e0 = seg_start[g], e1 = seg_start[g + 1];
    if (e1 <= e0) return;                       // uniform across block
    const int e1m1 = e1 - 1;
    const float gf = (float)g;

    for (int e = e0 + tid; e < e1; e += 256) out[E + e] = gf;   // coalesced

    float s0 = 0.f, s1 = 0.f, s2 = 0.f, s3 = 0.f;
    for (int e = e0 + wid * 4 + sub; e < e1; e += 64) {
        #pragma unroll
        for (int j = 0; j < 4; ++j) {
            int ee = e + j * 16;
            int ec = min(ee, e1m1);
            int i0 = hidx[ec], i1 = hidx[E + ec], i2 = hidx[2 * E + ec];
            uint2 A0 = *(const uint2*)(hb + (size_t)i0 * 64 + cl * 4);
            uint2 A1 = *(const uint2*)(hb + (size_t)i1 * 64 + cl * 4);
            uint2 A2 = *(const uint2*)(hb + (size_t)i2 * 64 + cl * 4);
            if (ee < e1) {
                s0 += __expf(b2f(f2b(blo(A0.x) + blo(A1.x) + blo(A2.x))));
                s1 += __expf(b2f(f2b(bhi(A0.x) + bhi(A1.x) + bhi(A2.x))));
                s2 += __expf(b2f(f2b(blo(A0.y) + blo(A1.y) + blo(A2.y))));
                s3 += __expf(b2f(f2b(bhi(A0.y) + bhi(A1.y) + bhi(A2.y))));
            }
        }
    }
    // reduce over sub (lane bits 4,5) then over waves
    s0 += __shfl_xor(s0, 16); s0 += __shfl_xor(s0, 32);
    s1 += __shfl_xor(s1, 16); s1 += __shfl_xor(s1, 32);
    s2 += __shfl_xor(s2, 16); s2 += __shfl_xor(s2, 32);
    s3 += __shfl_xor(s3, 16); s3 += __shfl_xor(s3, 32);
    if (lane < 16) {
        ps[wid][cl][0] = s0; ps[wid][cl][1] = s1;
        ps[wid][cl][2] = s2; ps[wid][cl][3] = s3;
    }
    __syncthreads();
    if (tid < 64) {
        int c4 = tid >> 2, cc = tid & 3;
        float S = ps[0][c4][cc] + ps[1][c4][cc] + ps[2][c4][cc] + ps[3][c4][cc];
        Sinv[g * 64 + tid] = 1.f / S;
    }
}

// ---------------------------------------------------------------------------
// K4: MFMA chain. 512-thread blocks, TWO segments per block (waves 0-3 ->
// seg 2b, waves 4-7 -> seg 2b+1) sharing one SW staging -> LDS 59392 B,
// 2 blocks/CU = 16 waves (was 12). A-frags re-gathered from L2-resident hb
// (6 uint4 + add3pack per lane per tile; quad-lanes coalesce to 64B
// segments) -- removes the 294 MB Xh HBM round trip. Next-tile hidx
// prefetched. Weights all in LDS (R5 lesson). xv via identity-MFMA (exact).
// ---------------------------------------------------------------------------
__global__ __launch_bounds__(512, 4) void mfma_seg_kernel(
    const u16* __restrict__ hb, const int* __restrict__ hidx,
    const int* __restrict__ seg_start,
    const u16* __restrict__ SWZ, const float* __restrict__ Sinv,
    const float* __restrict__ c1g, const float* __restrict__ c2g,
    const float* __restrict__ V3g, const float* __restrict__ c3g,
    float* __restrict__ out, int E, int G)
{
    __shared__ u16 SW[20480];          // WB[0,5120)+V1B[5120,15360)+V2B[15360,20480)
    __shared__ u16 XT_all[8][16 * 72]; // per-wave transpose tile

    const int tid = threadIdx.x, lane = tid & 63, wid = tid >> 6;  // wid 0..7
    const int nl = lane & 15, rq = lane >> 4;
    const int wl = wid & 3;
    const int g = blockIdx.x * 2 + (wid >> 2);

    {   // stage pre-swizzled W+V1+V2: 40960 B = 2560 uint4 over 512 threads
        const uint4* src = (const uint4*)SWZ;
        uint4* dst = (uint4*)SW;
        for (int i = tid; i < 2560; i += 512) dst[i] = src[i];
    }
    __syncthreads();                    // only barrier; safe to return after

    if (g >= G) return;
    const int e0 = seg_start[g], e1 = seg_start[g + 1];
    const int L = e1 - e0;
    if (L <= 0) return;
    const int e1m1 = e1 - 1;

    const u16* WB  = SW;
    const u16* V1B = SW + 5120;
    const u16* V2B = SW + 15360;

    // identity B-frags for X C-layout redistribution (exact in bf16)
    bf16x8 I0, I1;
    #pragma unroll
    for (int j = 0; j < 8; ++j) {
        I0[j] = (rq * 8 + j == nl)      ? (short)0x3F80 : (short)0;
        I1[j] = (rq * 8 + j == nl + 16) ? (short)0x3F80 : (short)0;
    }

    float dinvv[4], c1v[4], c2v[4], v3v[4];
    #pragma unroll
    for (int nt = 0; nt < 4; ++nt) {
        int col = nt * 16 + nl;
        dinvv[nt] = Sinv[g * 64 + col];
        c1v[nt]   = c1g[col];
        c2v[nt]   = c2g[col];
        v3v[nt]   = V3g[col];
    }
    const float c3s = c3g[0];
    u16* XT = XT_all[wid];
    const f32x4 zf = {0.f, 0.f, 0.f, 0.f};

    int t = wl;
    int i0c = 0, i1c = 0, i2c = 0;
    if (t * 16 < L) {
        int ec = min(e0 + t * 16 + nl, e1m1);
        i0c = hidx[ec]; i1c = hidx[E + ec]; i2c = hidx[2 * E + ec];
    }

    for (; t * 16 < L; t += 4) {
        const int eB = e0 + t * 16;

        // gather current tile's 3 rows (L2-resident hb), both feature halves
        const u16* r0 = hb + (size_t)i0c * 64 + rq * 8;
        const u16* r1 = hb + (size_t)i1c * 64 + rq * 8;
        const u16* r2 = hb + (size_t)i2c * 64 + rq * 8;
        uint4 p0 = *(const uint4*)r0, q0 = *(const uint4*)(r0 + 32);
        uint4 p1 = *(const uint4*)r1, q1 = *(const uint4*)(r1 + 32);
        uint4 p2 = *(const uint4*)r2, q2 = *(const uint4*)(r2 + 32);

        // prefetch next tile's indices
        const int tn = t + 4;
        if (tn * 16 < L) {
            int ec = min(e0 + tn * 16 + nl, e1m1);
            i0c = hidx[ec]; i1c = hidx[E + ec]; i2c = hidx[2 * E + ec];
        }

        // pack A-frags: a = f2b(h[i0]+h[i1]+h[i2])  (same order as K3)
        union { uint4 u; bf16x8 v; } ua0, ua1;
        ua0.u.x = add3pack(p0.x, p1.x, p2.x);
        ua0.u.y = add3pack(p0.y, p1.y, p2.y);
        ua0.u.z = add3pack(p0.z, p1.z, p2.z);
        ua0.u.w = add3pack(p0.w, p1.w, p2.w);
        ua1.u.x = add3pack(q0.x, q1.x, q2.x);
        ua1.u.y = add3pack(q0.y, q1.y, q2.y);
        ua1.u.z = add3pack(q0.z, q1.z, q2.z);
        ua1.u.w = add3pack(q0.w, q1.w, q2.w);
        const bf16x8 a0 = ua0.v, a1 = ua1.v;

        // xv in C-layout via identity MFMA (matrix pipe, overlaps layer W)
        f32x4 xc[4];
        xc[0] = MFMA16(a0, I0, zf, 0, 0, 0);
        xc[1] = MFMA16(a0, I1, zf, 0, 0, 0);
        xc[2] = MFMA16(a1, I0, zf, 0, 0, 0);
        xc[3] = MFMA16(a1, I1, zf, 0, 0, 0);

        // ---- layer W: acc = X @ W ----
        f32x4 acc[4] = {zf, zf, zf, zf};
        #pragma unroll
        for (int nt = 0; nt < 4; ++nt) {
            bf16x8 b0 = *(const bf16x8*)(WB + (0 * 4 + nt) * 640 + nl * 40 + rq * 8);
            acc[nt] = MFMA16(a0, b0, acc[nt], 0, 0, 0);
            bf16x8 b1 = *(const bf16x8*)(WB + (1 * 4 + nt) * 640 + nl * 40 + rq * 8);
            acc[nt] = MFMA16(a1, b1, acc[nt], 0, 0, 0);
        }
        // epilogue: Xhat = exp(xv)*dinv * relu(acc) -> XT
        #pragma unroll
        for (int nt = 0; nt < 4; ++nt) {
            #pragma unroll
            for (int r = 0; r < 4; ++r) {
                float coef = __expf(xc[nt][r]) * dinvv[nt];
                XT[(rq * 4 + r) * 72 + nt * 16 + nl] =
                    f2b(coef * fmaxf(acc[nt][r], 0.f));
            }
        }
        bf16x8 x2 = *(const bf16x8*)(XT + nl * 72 + rq * 8);
        bf16x8 x3 = *(const bf16x8*)(XT + nl * 72 + 32 + rq * 8);

        // ---- layer V1: acc2 = [X ; Xhat] @ V1 + c1 ----
        f32x4 acc2[4];
        #pragma unroll
        for (int nt = 0; nt < 4; ++nt) {
            acc2[nt][0] = c1v[nt]; acc2[nt][1] = c1v[nt];
            acc2[nt][2] = c1v[nt]; acc2[nt][3] = c1v[nt];
        }
        #pragma unroll
        for (int nt = 0; nt < 4; ++nt) {
            bf16x8 b0 = *(const bf16x8*)(V1B + (0 * 4 + nt) * 640 + nl * 40 + rq * 8);
            acc2[nt] = MFMA16(a0, b0, acc2[nt], 0, 0, 0);
            bf16x8 b1 = *(const bf16x8*)(V1B + (1 * 4 + nt) * 640 + nl * 40 + rq * 8);
            acc2[nt] = MFMA16(a1, b1, acc2[nt], 0, 0, 0);
        }
        #pragma unroll
        for (int nt = 0; nt < 4; ++nt) {
            bf16x8 b2 = *(const bf16x8*)(V1B + (2 * 4 + nt) * 640 + nl * 40 + rq * 8);
            acc2[nt] = MFMA16(x2, b2, acc2[nt], 0, 0, 0);
            bf16x8 b3 = *(const bf16x8*)(V1B + (3 * 4 + nt) * 640 + nl * 40 + rq * 8);
            acc2[nt] = MFMA16(x3, b3, acc2[nt], 0, 0, 0);
        }
        // epilogue: O1 = relu(acc2) -> XT
        #pragma unroll
        for (int nt = 0; nt < 4; ++nt) {
            #pragma unroll
            for (int r = 0; r < 4; ++r)
                XT[(rq * 4 + r) * 72 + nt * 16 + nl] = f2b(fmaxf(acc2[nt][r], 0.f));
        }
        bf16x8 o0 = *(const bf16x8*)(XT + nl * 72 + rq * 8);
        bf16x8 o1 = *(const bf16x8*)(XT + nl * 72 + 32 + rq * 8);

        // ---- layer V2: acc3 = O1 @ V2 + c2 (B-frags from LDS) ----
        f32x4 acc3[4];
        #pragma unroll
        for (int nt = 0; nt < 4; ++nt) {
            acc3[nt][0] = c2v[nt]; acc3[nt][1] = c2v[nt];
            acc3[nt][2] = c2v[nt]; acc3[nt][3] = c2v[nt];
        }
        #pragma unroll
        for (int nt = 0; nt < 4; ++nt) {
            bf16x8 b0 = *(const bf16x8*)(V2B + (0 * 4 + nt) * 640 + nl * 40 + rq * 8);
            acc3[nt] = MFMA16(o0, b0, acc3[nt], 0, 0, 0);
            bf16x8 b1 = *(const bf16x8*)(V2B + (1 * 4 + nt) * 640 + nl * 40 + rq * 8);
            acc3[nt] = MFMA16(o1, b1, acc3[nt], 0, 0, 0);
        }

        // ---- V3 + sigmoid ----
        float sr[4];
        #pragma unroll
        for (int r = 0; r < 4; ++r) {
            float v = 0.f;
            #pragma unroll
            for (int nt = 0; nt < 4; ++nt)
                v = fmaf(fmaxf(acc3[nt][r], 0.f), v3v[nt], v);
            v += __shfl_xor(v, 1);
            v += __shfl_xor(v, 2);
            v += __shfl_xor(v, 4);
            v += __shfl_xor(v, 8);
            sr[r] = v;
        }
        if (nl == 0) {
            #pragma unroll
            for (int r = 0; r < 4; ++r) {
                int e = eB + rq * 4 + r;
                if (e < e1) out[e] = 1.f / (1.f + __expf(-(sr[r] + c3s)));
            }
        }
    }
}

// ---------------------------------------------------------------------------
extern "C" void kernel_launch(void* const* d_in, const int* in_sizes, int n_in,
                              void* d_out, int out_size, void* d_ws, size_t ws_size,
                              hipStream_t stream) {
    const float* x     = (const float*)d_in[0];
    const float* u     = (const float*)d_in[1];
    const int*   batch = (const int*)  d_in[2];
    const int*   hidx  = (const int*)  d_in[3];
    const int*   bh    = (const int*)  d_in[4];
    const float* W1 = (const float*)d_in[6];
    const float* b1 = (const float*)d_in[7];
    const float* W2 = (const float*)d_in[8];
    const float* b2 = (const float*)d_in[9];
    const float* W3 = (const float*)d_in[10];
    const float* b3 = (const float*)d_in[11];
    const float* Wg = (const float*)d_in[12];
    const float* V1 = (const float*)d_in[13];
    const float* c1 = (const float*)d_in[14];
    const float* V2 = (const float*)d_in[15];
    const float* c2 = (const float*)d_in[16];
    const float* V3 = (const float*)d_in[17];
    const float* c3 = (const float*)d_in[18];

    const int N = in_sizes[0] / 6;
    const int G = in_sizes[1] / 4;
    const int E = in_sizes[4];

    // ws layout
    char* ws = (char*)d_ws;
    size_t off = 0;
    u16* hb = (u16*)(ws + off);            off += (size_t)N * 64 * 2;
    int* seg_start = (int*)(ws + off);     off += ((size_t)G + 1) * 4;
    off = (off + 255) & ~(size_t)255;
    u16* SWZ = (u16*)(ws + off);           off += 20480 * 2;
    float* Sinv = (float*)(ws + off);      off += (size_t)G * 64 * 4;
    float* out = (float*)d_out;

    swizzle_weights<<<32, 256, 0, stream>>>(Wg, V1, V2, SWZ);
    node_mlp_kernel<<<(N + 3) / 4, 256, 0, stream>>>(
        x, u, batch, W1, b1, W2, b2, W3, b3, hb, N);
    seg_bounds_kernel<<<(G + 256) / 256, 256, 0, stream>>>(bh, E, G, seg_start);
    gather_stats_kernel<<<G, 256, 0, stream>>>(hb, hidx, seg_start, Sinv, out, E);
    mfma_seg_kernel<<<(G + 1) / 2, 512, 0, stream>>>(
        hb, hidx, seg_start, SWZ, Sinv, c1, c2, V3, c3, out, E, G);
}

// Round 8
// 419.707 us; speedup vs baseline: 1.1660x; 1.1660x over previous
//
#include <hip/hip_runtime.h>
#include <math.h>

typedef short bf16x8 __attribute__((ext_vector_type(8)));
typedef float f32x4  __attribute__((ext_vector_type(4)));
typedef unsigned short u16;
typedef unsigned int   u32;

#define MFMA16 __builtin_amdgcn_mfma_f32_16x16x32_bf16

__device__ __forceinline__ u16 f2b(float x) {   // fp32 -> bf16 RNE
    union { float f; unsigned u; } v; v.f = x;
    unsigned r = v.u + 0x7fffu + ((v.u >> 16) & 1u);
    return (u16)(r >> 16);
}
__device__ __forceinline__ float b2f(u16 h) {
    union { unsigned u; float f; } v; v.u = ((unsigned)h) << 16;
    return v.f;
}
__device__ __forceinline__ float blo(u32 w) {
    union { u32 u; float f; } v; v.u = w << 16; return v.f;
}
__device__ __forceinline__ float bhi(u32 w) {
    union { u32 u; float f; } v; v.u = w & 0xffff0000u; return v.f;
}
// sum 3 packed bf16 pairs in fp32 (order i0+i1+i2), repack bf16
__device__ __forceinline__ u32 add3pack(u32 x, u32 y, u32 z) {
    float lo = blo(x) + blo(y) + blo(z);
    float hi = bhi(x) + bhi(y) + bhi(z);
    return (u32)f2b(lo) | ((u32)f2b(hi) << 16);
}

// ---------------------------------------------------------------------------
// K0: pre-swizzle weights (bf16, B-fragment panel layout) into global ws.
// Panel(kt,nt): 16 n-rows x 40 u16 (pad 32->40). SWZ layout:
//   WB [0,5120) | V1B [5120,15360) | V2B [15360,20480)
// ---------------------------------------------------------------------------
__global__ __launch_bounds__(256) void swizzle_weights(
    const float* __restrict__ Wg, const float* __restrict__ V1g,
    const float* __restrict__ V2g, u16* __restrict__ SWZ)
{
    int idx = blockIdx.x * 256 + threadIdx.x;       // 0..8191
    int k = idx >> 6, n = idx & 63;
    int off = ((k >> 5) * 4 + (n >> 4)) * 640 + (n & 15) * 40 + ((k >> 3) & 3) * 8 + (k & 7);
    SWZ[5120 + off] = f2b(V1g[idx]);
    if (idx < 4096) {
        SWZ[off]         = f2b(Wg[idx]);
        SWZ[15360 + off] = f2b(V2g[idx]);
    }
}

// ---------------------------------------------------------------------------
// K1: node MLP -> hb (bf16) [N,64]
// ---------------------------------------------------------------------------
__global__ __launch_bounds__(256) void node_mlp_kernel(
    const float* __restrict__ x, const float* __restrict__ u,
    const int* __restrict__ batch,
    const float* __restrict__ W1, const float* __restrict__ b1,
    const float* __restrict__ W2, const float* __restrict__ b2,
    const float* __restrict__ W3, const float* __restrict__ b3,
    u16* __restrict__ hb, int N)
{
    __shared__ float inbuf[4][10];
    __shared__ float h1[4][64];
    __shared__ float h2[4][64];
    const int tid = threadIdx.x;
    const int ni = tid >> 6, f = tid & 63;
    int node = blockIdx.x * 4 + ni;
    if (node >= N) node = N - 1;
    if (f < 6)       inbuf[ni][f] = x[node * 6 + f];
    else if (f < 10) inbuf[ni][f] = u[batch[node] * 4 + (f - 6)];
    __syncthreads();
    float acc = b1[f];
    #pragma unroll
    for (int k = 0; k < 10; ++k) acc = fmaf(inbuf[ni][k], W1[k * 64 + f], acc);
    h1[ni][f] = fmaxf(acc, 0.f);
    __syncthreads();
    acc = b2[f];
    #pragma unroll 16
    for (int k = 0; k < 64; ++k) acc = fmaf(h1[ni][k], W2[k * 64 + f], acc);
    h2[ni][f] = fmaxf(acc, 0.f);
    __syncthreads();
    acc = b3[f];
    #pragma unroll 16
    for (int k = 0; k < 64; ++k) acc = fmaf(h2[ni][k], W3[k * 64 + f], acc);
    hb[node * 64 + f] = f2b(acc);
}

// ---------------------------------------------------------------------------
// K2: segment boundaries (batch_hyper sorted)
// ---------------------------------------------------------------------------
__global__ __launch_bounds__(256) void seg_bounds_kernel(
    const int* __restrict__ bh, int E, int G, int* __restrict__ seg_start)
{
    int g = blockIdx.x * blockDim.x + threadIdx.x;
    if (g > G) return;
    int lo = 0, hi = E;
    while (lo < hi) {
        int mid = (lo + hi) >> 1;
        if (bh[mid] < g) lo = mid + 1; else hi = mid;
    }
    seg_start[g] = lo;
}

// ---------------------------------------------------------------------------
// K3 (fused): one block per segment, two phases.
//  Phase 1 (ex-gather_stats): gather x_hyper from hb (random, once), write
//    Xh stream (coalesced uint2), accumulate softmax denominators; reduce
//    in LDS. Also writes out[E..2E) = (float)g.
//  Phase 2 (= R6 K4, verified 186us): 16-edge MFMA tiles, Xh read streaming
//    with 1-deep prefetch (L2-hot: this block just wrote it), all weights in
//    LDS (R5 lesson), xv via identity-MFMA (exact), XT C->A transposes.
//  Fusion rationale: different resident blocks sit in different phases ->
//  gather/VALU/exp work overlaps DS/MFMA work on the same CU (m114), and
//  the Xh round trip becomes same-XCD-L2-local. R7 lesson: never re-gather
//  randomly in the MFMA loop.
// LDS: 40960(SW) + 9216(XT) + 1024(ps) + 256(SfInv) = 51456 B -> 3 blocks/CU.
// ---------------------------------------------------------------------------
__global__ __launch_bounds__(256, 3) void fused_seg_kernel(
    const u16* __restrict__ hb, const int* __restrict__ hidx,
    const int* __restrict__ seg_start,
    const u16* __restrict__ SWZ,
    const float* __restrict__ c1g, const float* __restrict__ c2g,
    const float* __restrict__ V3g, const float* __restrict__ c3g,
    u16* __restrict__ Xh, float* __restrict__ out, int E)
{
    __shared__ u16 SW[20480];          // WB[0,5120)+V1B[5120,15360)+V2B[15360,20480)
    __shared__ u16 XT_all[4][16 * 72]; // per-wave transpose tile
    __shared__ float ps[4][16][4];
    __shared__ float SfInv[64];

    const int tid = threadIdx.x, lane = tid & 63, wid = tid >> 6;
    const int nl = lane & 15, rq = lane >> 4;
    const int g = blockIdx.x;
    const int e0 = seg_start[g], e1 = seg_start[g + 1];
    const int L = e1 - e0;
    const int e1m1 = e1 - 1;

    {   // stage pre-swizzled W+V1+V2: 40960 B = 2560 uint4
        const uint4* src = (const uint4*)SWZ;
        uint4* dst = (uint4*)SW;
        for (int i = tid; i < 2560; i += 256) dst[i] = src[i];
    }
    __syncthreads();
    if (L <= 0) return;                 // block-uniform

    // ================= phase 1: gather + stats + Xh stream ==============
    const float gf = (float)g;
    for (int e = e0 + tid; e < e1; e += 256) out[E + e] = gf;   // coalesced

    {
        const int sub = lane >> 4, cl = lane & 15;
        float s0 = 0.f, s1 = 0.f, s2 = 0.f, s3 = 0.f;
        for (int t = wid; t * 16 < L; t += 4) {
            const int eB = e0 + t * 16;
            #pragma unroll
            for (int j = 0; j < 4; ++j) {
                int ee = eB + j * 4 + sub;
                int ec = min(ee, e1m1);
                int i0 = hidx[ec], i1 = hidx[E + ec], i2 = hidx[2 * E + ec];
                uint2 A0 = *(const uint2*)(hb + (size_t)i0 * 64 + cl * 4);
                uint2 A1 = *(const uint2*)(hb + (size_t)i1 * 64 + cl * 4);
                uint2 A2 = *(const uint2*)(hb + (size_t)i2 * 64 + cl * 4);
                u32 wx = add3pack(A0.x, A1.x, A2.x);
                u32 wy = add3pack(A0.y, A1.y, A2.y);
                if (ee < e1) {
                    uint2 W; W.x = wx; W.y = wy;
                    *(uint2*)(Xh + (size_t)ee * 64 + cl * 4) = W;
                    s0 += __expf(blo(wx)); s1 += __expf(bhi(wx));
                    s2 += __expf(blo(wy)); s3 += __expf(bhi(wy));
                }
            }
        }
        // reduce over sub (lane bits 4,5), then across waves via LDS
        s0 += __shfl_xor(s0, 16); s0 += __shfl_xor(s0, 32);
        s1 += __shfl_xor(s1, 16); s1 += __shfl_xor(s1, 32);
        s2 += __shfl_xor(s2, 16); s2 += __shfl_xor(s2, 32);
        s3 += __shfl_xor(s3, 16); s3 += __shfl_xor(s3, 32);
        if (lane < 16) {
            ps[wid][cl][0] = s0; ps[wid][cl][1] = s1;
            ps[wid][cl][2] = s2; ps[wid][cl][3] = s3;
        }
    }
    __syncthreads();
    if (tid < 64) {
        int c4 = tid >> 2, cc = tid & 3;
        float S = ps[0][c4][cc] + ps[1][c4][cc] + ps[2][c4][cc] + ps[3][c4][cc];
        SfInv[tid] = 1.f / S;
    }
    __syncthreads();

    // ================= phase 2: MFMA chain (R6-verified) =================
    const u16* WB  = SW;
    const u16* V1B = SW + 5120;
    const u16* V2B = SW + 15360;

    // identity B-frags for X C-layout redistribution (exact in bf16)
    bf16x8 I0, I1;
    #pragma unroll
    for (int j = 0; j < 8; ++j) {
        I0[j] = (rq * 8 + j == nl)      ? (short)0x3F80 : (short)0;
        I1[j] = (rq * 8 + j == nl + 16) ? (short)0x3F80 : (short)0;
    }

    float dinvv[4], c1v[4], c2v[4], v3v[4];
    #pragma unroll
    for (int nt = 0; nt < 4; ++nt) {
        int col = nt * 16 + nl;
        dinvv[nt] = SfInv[col];
        c1v[nt]   = c1g[col];
        c2v[nt]   = c2g[col];
        v3v[nt]   = V3g[col];
    }
    const float c3s = c3g[0];
    u16* XT = XT_all[wid];
    const f32x4 zf = {0.f, 0.f, 0.f, 0.f};

    int t = wid;
    bf16x8 a0 = {}, a1 = {};
    if (t * 16 < L) {
        const u16* xp = Xh + (size_t)min(e0 + t * 16 + nl, e1m1) * 64 + rq * 8;
        a0 = *(const bf16x8*)(xp);
        a1 = *(const bf16x8*)(xp + 32);
    }

    for (; t * 16 < L; t += 4) {
        const int eB = e0 + t * 16;
        const int tn = t + 4;
        bf16x8 n0 = {}, n1 = {};
        if (tn * 16 < L) {  // prefetch next tile (wave-uniform branch)
            const u16* xp = Xh + (size_t)min(e0 + tn * 16 + nl, e1m1) * 64 + rq * 8;
            n0 = *(const bf16x8*)(xp);
            n1 = *(const bf16x8*)(xp + 32);
        }

        // xv in C-layout via identity MFMA (matrix pipe, overlaps layer W)
        f32x4 xc[4];
        xc[0] = MFMA16(a0, I0, zf, 0, 0, 0);
        xc[1] = MFMA16(a0, I1, zf, 0, 0, 0);
        xc[2] = MFMA16(a1, I0, zf, 0, 0, 0);
        xc[3] = MFMA16(a1, I1, zf, 0, 0, 0);

        // ---- layer W: acc = X @ W ----
        f32x4 acc[4] = {zf, zf, zf, zf};
        #pragma unroll
        for (int nt = 0; nt < 4; ++nt) {
            bf16x8 b0 = *(const bf16x8*)(WB + (0 * 4 + nt) * 640 + nl * 40 + rq * 8);
            acc[nt] = MFMA16(a0, b0, acc[nt], 0, 0, 0);
            bf16x8 b1 = *(const bf16x8*)(WB + (1 * 4 + nt) * 640 + nl * 40 + rq * 8);
            acc[nt] = MFMA16(a1, b1, acc[nt], 0, 0, 0);
        }
        // epilogue: Xhat = exp(xv)*dinv * relu(acc) -> XT
        #pragma unroll
        for (int nt = 0; nt < 4; ++nt) {
            #pragma unroll
            for (int r = 0; r < 4; ++r) {
                float coef = __expf(xc[nt][r]) * dinvv[nt];
                XT[(rq * 4 + r) * 72 + nt * 16 + nl] =
                    f2b(coef * fmaxf(acc[nt][r], 0.f));
            }
        }
        bf16x8 x2 = *(const bf16x8*)(XT + nl * 72 + rq * 8);
        bf16x8 x3 = *(const bf16x8*)(XT + nl * 72 + 32 + rq * 8);

        // ---- layer V1: acc2 = [X ; Xhat] @ V1 + c1 ----
        f32x4 acc2[4];
        #pragma unroll
        for (int nt = 0; nt < 4; ++nt) {
            acc2[nt][0] = c1v[nt]; acc2[nt][1] = c1v[nt];
            acc2[nt][2] = c1v[nt]; acc2[nt][3] = c1v[nt];
        }
        #pragma unroll
        for (int nt = 0; nt < 4; ++nt) {
            bf16x8 b0 = *(const bf16x8*)(V1B + (0 * 4 + nt) * 640 + nl * 40 + rq * 8);
            acc2[nt] = MFMA16(a0, b0, acc2[nt], 0, 0, 0);
            bf16x8 b1 = *(const bf16x8*)(V1B + (1 * 4 + nt) * 640 + nl * 40 + rq * 8);
            acc2[nt] = MFMA16(a1, b1, acc2[nt], 0, 0, 0);
        }
        #pragma unroll
        for (int nt = 0; nt < 4; ++nt) {
            bf16x8 b2 = *(const bf16x8*)(V1B + (2 * 4 + nt) * 640 + nl * 40 + rq * 8);
            acc2[nt] = MFMA16(x2, b2, acc2[nt], 0, 0, 0);
            bf16x8 b3 = *(const bf16x8*)(V1B + (3 * 4 + nt) * 640 + nl * 40 + rq * 8);
            acc2[nt] = MFMA16(x3, b3, acc2[nt], 0, 0, 0);
        }
        // epilogue: O1 = relu(acc2) -> XT
        #pragma unroll
        for (int nt = 0; nt < 4; ++nt) {
            #pragma unroll
            for (int r = 0; r < 4; ++r)
                XT[(rq * 4 + r) * 72 + nt * 16 + nl] = f2b(fmaxf(acc2[nt][r], 0.f));
        }
        bf16x8 o0 = *(const bf16x8*)(XT + nl * 72 + rq * 8);
        bf16x8 o1 = *(const bf16x8*)(XT + nl * 72 + 32 + rq * 8);

        // ---- layer V2: acc3 = O1 @ V2 + c2 (B-frags from LDS) ----
        f32x4 acc3[4];
        #pragma unroll
        for (int nt = 0; nt < 4; ++nt) {
            acc3[nt][0] = c2v[nt]; acc3[nt][1] = c2v[nt];
            acc3[nt][2] = c2v[nt]; acc3[nt][3] = c2v[nt];
        }
        #pragma unroll
        for (int nt = 0; nt < 4; ++nt) {
            bf16x8 b0 = *(const bf16x8*)(V2B + (0 * 4 + nt) * 640 + nl * 40 + rq * 8);
            acc3[nt] = MFMA16(o0, b0, acc3[nt], 0, 0, 0);
            bf16x8 b1 = *(const bf16x8*)(V2B + (1 * 4 + nt) * 640 + nl * 40 + rq * 8);
            acc3[nt] = MFMA16(o1, b1, acc3[nt], 0, 0, 0);
        }

        // ---- V3 + sigmoid ----
        float sr[4];
        #pragma unroll
        for (int r = 0; r < 4; ++r) {
            float v = 0.f;
            #pragma unroll
            for (int nt = 0; nt < 4; ++nt)
                v = fmaf(fmaxf(acc3[nt][r], 0.f), v3v[nt], v);
            v += __shfl_xor(v, 1);
            v += __shfl_xor(v, 2);
            v += __shfl_xor(v, 4);
            v += __shfl_xor(v, 8);
            sr[r] = v;
        }
        if (nl == 0) {
            #pragma unroll
            for (int r = 0; r < 4; ++r) {
                int e = eB + rq * 4 + r;
                if (e < e1) out[e] = 1.f / (1.f + __expf(-(sr[r] + c3s)));
            }
        }
        a0 = n0; a1 = n1;
    }
}

// ---------------------------------------------------------------------------
extern "C" void kernel_launch(void* const* d_in, const int* in_sizes, int n_in,
                              void* d_out, int out_size, void* d_ws, size_t ws_size,
                              hipStream_t stream) {
    const float* x     = (const float*)d_in[0];
    const float* u     = (const float*)d_in[1];
    const int*   batch = (const int*)  d_in[2];
    const int*   hidx  = (const int*)  d_in[3];
    const int*   bh    = (const int*)  d_in[4];
    const float* W1 = (const float*)d_in[6];
    const float* b1 = (const float*)d_in[7];
    const float* W2 = (const float*)d_in[8];
    const float* b2 = (const float*)d_in[9];
    const float* W3 = (const float*)d_in[10];
    const float* b3 = (const float*)d_in[11];
    const float* Wg = (const float*)d_in[12];
    const float* V1 = (const float*)d_in[13];
    const float* c1 = (const float*)d_in[14];
    const float* V2 = (const float*)d_in[15];
    const float* c2 = (const float*)d_in[16];
    const float* V3 = (const float*)d_in[17];
    const float* c3 = (const float*)d_in[18];

    const int N = in_sizes[0] / 6;
    const int G = in_sizes[1] / 4;
    const int E = in_sizes[4];

    // ws layout
    char* ws = (char*)d_ws;
    size_t off = 0;
    u16* hb = (u16*)(ws + off);            off += (size_t)N * 64 * 2;
    int* seg_start = (int*)(ws + off);     off += ((size_t)G + 1) * 4;
    off = (off + 255) & ~(size_t)255;
    u16* SWZ = (u16*)(ws + off);           off += 20480 * 2;
    off = (off + 255) & ~(size_t)255;
    u16* Xh = (u16*)(ws + off);            off += (size_t)E * 64 * 2;
    float* out = (float*)d_out;

    swizzle_weights<<<32, 256, 0, stream>>>(Wg, V1, V2, SWZ);
    node_mlp_kernel<<<(N + 3) / 4, 256, 0, stream>>>(
        x, u, batch, W1, b1, W2, b2, W3, b3, hb, N);
    seg_bounds_kernel<<<(G + 256) / 256, 256, 0, stream>>>(bh, E, G, seg_start);
    fused_seg_kernel<<<G, 256, 0, stream>>>(
        hb, hidx, seg_start, SWZ, c1, c2, V3, c3, Xh, out, E);
}